// Round 4
// baseline (2260.324 us; speedup 1.0000x reference)
//
#include <hip/hip_runtime.h>

// Problem constants
#define BTOT 16384
#define NI   16
#define HD   256
#define BB   2            // batch elements per block
#define NROW (BB * NI)    // 32 GEMM rows per block
#define AS   (HD + 4)     // padded LDS row stride (16B-aligned)
#define NMID 3
#define HALF_LOGFACT 15.3359295387f  // 0.5 * ln(16!)

__device__ __forceinline__ float fast_tanh(float x) {
    float ax = __builtin_fabsf(x);
    float e  = __expf(-2.0f * ax);
    float t  = __fdividef(1.0f - e, 1.0f + e);
    return __builtin_copysignf(t, x);
}

struct SMem {
    float A[NROW][AS];            // 32*260*4 = 33280 B (single buffer, updated in place)
    float gm[BB][HD];             // 2048 B
    float gvec[BB][HD];           // 2048 B
    float sl[BB][NI][NI + 1];     // 2176 B
    float x0[NROW];               // 128 B
    float gmean[BB];              // 8 B
};
static_assert(sizeof(SMem) <= 65536, "LDS must fit the 64KB per-workgroup launch limit");

struct F4x4 { float4 v[4]; };
struct F4x8 { float4 v[8]; };

__device__ __forceinline__ void loadA(F4x4& a, const float (*Ab)[AS], int tr, int kc) {
#pragma unroll
    for (int rr = 0; rr < 4; ++rr)
        a.v[rr] = *(const float4*)&Ab[tr * 4 + rr][kc * 4];
}

__device__ __forceinline__ void loadB(F4x8& b, const float* __restrict__ Wl, int tc, int kc) {
#pragma unroll
    for (int kk = 0; kk < 4; ++kk) {
        const float* wp = Wl + (kc * 4 + kk) * HD + tc * 8;
        b.v[kk * 2]     = *(const float4*)(wp);
        b.v[kk * 2 + 1] = *(const float4*)(wp + 4);
    }
}

__device__ __forceinline__ void fma_block(float (&acc)[4][8], const F4x4& a, const F4x8& b) {
#pragma unroll
    for (int kk = 0; kk < 4; ++kk) {
        float bv[8];
#pragma unroll
        for (int q = 0; q < 2; ++q) {
            float4 bq = b.v[kk * 2 + q];
            bv[q * 4 + 0] = bq.x; bv[q * 4 + 1] = bq.y;
            bv[q * 4 + 2] = bq.z; bv[q * 4 + 3] = bq.w;
        }
#pragma unroll
        for (int rr = 0; rr < 4; ++rr) {
            float4 aq = a.v[rr];
            float av = (kk == 0) ? aq.x : (kk == 1) ? aq.y : (kk == 2) ? aq.z : aq.w;
#pragma unroll
            for (int jj = 0; jj < 8; ++jj)
                acc[rr][jj] = __builtin_fmaf(av, bv[jj], acc[rr][jj]);
        }
    }
}

__global__ __launch_bounds__(256, 2)
void eqslater_kernel(const float* __restrict__ x0g,
                     const float* __restrict__ Win,
                     const float* __restrict__ bin,
                     const float* __restrict__ Wmid,
                     const float* __restrict__ bmid,
                     const float* __restrict__ Wsl,
                     const float* __restrict__ bsl,
                     const float* __restrict__ width,
                     float* __restrict__ out) {
    __shared__ SMem sm;
    const int tid = threadIdx.x;
    const int bbase = blockIdx.x * BB;

    // ---- stage x0 tile ----
    if (tid < NROW) sm.x0[tid] = x0g[bbase * NI + tid];
    __syncthreads();
    if (tid < BB) {
        float s = 0.f;
#pragma unroll
        for (int n = 0; n < NI; ++n) s += sm.x0[tid * NI + n];
        sm.gmean[tid] = s * (1.0f / NI);
    }
    __syncthreads();

    // ---- input layer: h0[r][j] = tanh(x0*W0 + g*W1 + b) ----
    {
        const int j = tid;
        const float w0 = Win[j];
        const float w1 = Win[HD + j];
        const float bj = bin[j];
#pragma unroll 8
        for (int r = 0; r < NROW; ++r) {
            float pre = sm.x0[r] * w0 + sm.gmean[r >> 4] * w1 + bj;
            sm.A[r][j] = fast_tanh(pre);
        }
    }
    __syncthreads();

    const int tr = tid >> 5;   // 0..7 -> rows tr*4 .. tr*4+3
    const int tc = tid & 31;   // 0..31 -> cols tc*8 .. tc*8+7
    const int bb = tr >> 2;    // element index of this thread's rows

    for (int layer = 0; layer < NMID; ++layer) {
        const float* Wl = Wmid + layer * (2 * HD * HD);

        // ---- gm: column means over n per element ----
        {
            const int j = tid;
#pragma unroll
            for (int e = 0; e < BB; ++e) {
                float s = 0.f;
#pragma unroll
                for (int n = 0; n < NI; ++n) s += sm.A[e * NI + n][j];
                sm.gm[e][j] = s * (1.0f / NI);
            }
        }
        __syncthreads();

        // ---- gvec[e][j] = sum_k gm[e][k] * W_bot[k][j] + b ----
        {
            const int j = tid;
            const float bj = bmid[layer * HD + j];
            float acc0 = bj, acc1 = bj;
#pragma unroll 8
            for (int kc = 0; kc < HD / 4; ++kc) {
                float4 g0 = *(const float4*)&sm.gm[0][kc * 4];
                float4 g1 = *(const float4*)&sm.gm[1][kc * 4];
#pragma unroll
                for (int kk = 0; kk < 4; ++kk) {
                    float wv = Wl[(HD + kc * 4 + kk) * HD + j];
                    float e0 = (kk == 0) ? g0.x : (kk == 1) ? g0.y : (kk == 2) ? g0.z : g0.w;
                    float e1 = (kk == 0) ? g1.x : (kk == 1) ? g1.y : (kk == 2) ? g1.z : g1.w;
                    acc0 = __builtin_fmaf(e0, wv, acc0);
                    acc1 = __builtin_fmaf(e1, wv, acc1);
                }
            }
            sm.gvec[0][j] = acc0; sm.gvec[1][j] = acc1;
        }
        __syncthreads();

        // ---- main GEMM: acc[r][j] = sum_k A[r][k]*W_top[k][j], 32x256x256 ----
        float o[4][8];
        {
            float acc[4][8];
#pragma unroll
            for (int rr = 0; rr < 4; ++rr)
#pragma unroll
                for (int jj = 0; jj < 8; ++jj) acc[rr][jj] = 0.f;

            F4x4 a0, a1; F4x8 b0, b1;
            loadA(a0, sm.A, tr, 0); loadB(b0, Wl, tc, 0);
#pragma unroll 1
            for (int kc = 0; kc < 64; kc += 2) {
                loadA(a1, sm.A, tr, kc + 1); loadB(b1, Wl, tc, kc + 1);
                fma_block(acc, a0, b0);
                if (kc + 2 < 64) { loadA(a0, sm.A, tr, kc + 2); loadB(b0, Wl, tc, kc + 2); }
                fma_block(acc, a1, b1);
            }

            // epilogue (registers only): tanh(acc + gvec) + residual
            float4 gv0 = *(const float4*)&sm.gvec[bb][tc * 8];
            float4 gv1 = *(const float4*)&sm.gvec[bb][tc * 8 + 4];
            float gvv[8] = {gv0.x, gv0.y, gv0.z, gv0.w, gv1.x, gv1.y, gv1.z, gv1.w};
#pragma unroll
            for (int rr = 0; rr < 4; ++rr) {
                const int r = tr * 4 + rr;
                float4 r0 = *(const float4*)&sm.A[r][tc * 8];
                float4 r1 = *(const float4*)&sm.A[r][tc * 8 + 4];
                float res[8] = {r0.x, r0.y, r0.z, r0.w, r1.x, r1.y, r1.z, r1.w};
#pragma unroll
                for (int jj = 0; jj < 8; ++jj)
                    o[rr][jj] = fast_tanh(acc[rr][jj] + gvv[jj]) + res[jj];
            }
        }
        __syncthreads();   // all reads of A complete before in-place update
#pragma unroll
        for (int rr = 0; rr < 4; ++rr) {
            const int r = tr * 4 + rr;
            float4 o0 = {o[rr][0], o[rr][1], o[rr][2], o[rr][3]};
            float4 o1 = {o[rr][4], o[rr][5], o[rr][6], o[rr][7]};
            *(float4*)&sm.A[r][tc * 8]     = o0;
            *(float4*)&sm.A[r][tc * 8 + 4] = o1;
        }
        __syncthreads();
    }

    // ---- slater head: sl[r][m] = sum_k A[r][k]*Wsl[k][m] + bsl[m] ----
    {
        const int r2 = tid >> 3;   // 0..31 (block row)
        const int m2 = tid & 7;    // col group: cols m2*2, m2*2+1
        float s0 = bsl[m2 * 2], s1 = bsl[m2 * 2 + 1];
#pragma unroll 8
        for (int kc = 0; kc < HD / 4; ++kc) {
            float4 av = *(const float4*)&sm.A[r2][kc * 4];
            float avv[4] = {av.x, av.y, av.z, av.w};
#pragma unroll
            for (int kk = 0; kk < 4; ++kk) {
                float2 wv = *(const float2*)&Wsl[(kc * 4 + kk) * NI + m2 * 2];
                s0 = __builtin_fmaf(avv[kk], wv.x, s0);
                s1 = __builtin_fmaf(avv[kk], wv.y, s1);
            }
        }
        sm.sl[r2 >> 4][r2 & 15][m2 * 2]     = s0;
        sm.sl[r2 >> 4][r2 & 15][m2 * 2 + 1] = s1;
    }
    __syncthreads();

    // ---- per-wave slogdet: register LU w/ partial pivoting ----
    // wave w owns element w (w < BB); lane l holds row i = l&15 (4x duplicated)
    const int w = tid >> 6;
    const int l = tid & 63;
    const int i = l & 15;

    if (w < BB) {
        float M[16];
#pragma unroll
        for (int j = 0; j < 16; ++j) M[j] = sm.sl[w][i][j];

        float dsign = 1.f, logabs = 0.f;
#pragma unroll
        for (int k = 0; k < 16; ++k) {
            // column-k pivot search: butterfly max, then ballot for first max row
            float myv = (i >= k) ? __builtin_fabsf(M[k]) : -1.f;
            float maxv = myv;
#pragma unroll
            for (int off = 32; off > 0; off >>= 1)
                maxv = fmaxf(maxv, __shfl_xor(maxv, off));
            unsigned long long bal = __ballot(myv == maxv);
            int p = (__ffsll((long long)bal) - 1) & 15;   // first (lowest) row with max

            if (p != k) {
                dsign = -dsign;
#pragma unroll
                for (int j = 0; j < 16; ++j) {
                    float vk = __shfl(M[j], k);
                    float vp = __shfl(M[j], p);
                    if (i == k) M[j] = vp;
                    if (i == p) M[j] = vk;
                }
            }
            float piv = __shfl(M[k], k);
            // NaN/inf guard: exact-zero pivot (singular matrix) must yield a
            // FINITE logabs (ref gives -inf; |finite - (-inf)| = inf passes the
            // inf threshold, while -inf - -inf = NaN fails it) and must not
            // poison remaining rows via 0/0.
            float ap  = fmaxf(__builtin_fabsf(piv), 1e-35f);
            logabs += __logf(ap);
            if (piv < 0.f) dsign = -dsign;
            float spiv = __builtin_copysignf(ap, piv);
            float mi = __fdividef(M[k], spiv);
#pragma unroll
            for (int j = k + 1; j < 16; ++j) {
                float vkj = __shfl(M[j], k);
                if (i > k) M[j] = __builtin_fmaf(-mi, vkj, M[j]);
            }
        }

        // ---- log_bcs and output ----
        float xv = (l < NI) ? sm.x0[w * NI + l] : 0.f;
        float sq = xv * xv;
#pragma unroll
        for (int off = 8; off > 0; off >>= 1) sq += __shfl_xor(sq, off);

        if (l == 0) {
            out[bbase + w] = dsign;
            out[BTOT + bbase + w] = logabs - HALF_LOGFACT - width[0] * sq;
        }
    }
}

extern "C" void kernel_launch(void* const* d_in, const int* in_sizes, int n_in,
                              void* d_out, int out_size, void* d_ws, size_t ws_size,
                              hipStream_t stream) {
    const float* x0   = (const float*)d_in[0];
    const float* Win  = (const float*)d_in[1];
    const float* bin  = (const float*)d_in[2];
    const float* Wmid = (const float*)d_in[3];
    const float* bmid = (const float*)d_in[4];
    const float* Wsl  = (const float*)d_in[5];
    const float* bsl  = (const float*)d_in[6];
    const float* wid  = (const float*)d_in[7];
    float* out = (float*)d_out;

    dim3 grid(BTOT / BB);
    dim3 block(256);
    hipLaunchKernelGGL(eqslater_kernel, grid, block, 0, stream,
                       x0, Win, bin, Wmid, bmid, Wsl, bsl, wid, out);
}

// Round 5
// 1382.383 us; speedup vs baseline: 1.6351x; 1.6351x over previous
//
#include <hip/hip_runtime.h>

// Problem constants
#define BTOT 16384
#define NI   16
#define HD   256
#define K2   512          // concat K (h:256 + gm:256)
#define BB   4            // elements per block = waves per block
#define NMID 3
#define ASH  264          // h LDS row stride in bf16 elems (528B, 16B-aligned)
#define HALF_LOGFACT 15.3359295387f  // 0.5 * ln(16!)

typedef short  bf16x8 __attribute__((ext_vector_type(8)));
typedef float  f32x4  __attribute__((ext_vector_type(4)));

__device__ __forceinline__ unsigned short f2bf(float f) {
    unsigned u = __builtin_bit_cast(unsigned, f);
    u += 0x7FFFu + ((u >> 16) & 1u);          // RNE
    return (unsigned short)(u >> 16);
}
__device__ __forceinline__ float bf2f(unsigned short h) {
    return __builtin_bit_cast(float, (unsigned)h << 16);
}
__device__ __forceinline__ float fast_tanh(float x) {
    float ax = __builtin_fabsf(x);
    float e  = __expf(-2.0f * ax);
    float t  = __fdividef(1.0f - e, 1.0f + e);
    return __builtin_copysignf(t, x);
}

// ---- prep: Wt[l][j][k] = bf16(Wmid[l][k][j])  (B operand wants k-contiguous per col)
__global__ void prep_wt(const float* __restrict__ Wmid, unsigned short* __restrict__ wt) {
    __shared__ float t[32][33];
    const int tid = threadIdx.x;
    const int b = blockIdx.x;
    const int l = b >> 7, rem = b & 127, kt = rem >> 3, jt = rem & 7;
    {
        const int r = tid >> 3, jg = tid & 7;   // k-row r, j-group
        float4 v = *(const float4*)&Wmid[(size_t)(l * K2 + kt * 32 + r) * HD + jt * 32 + jg * 4];
        t[r][jg * 4 + 0] = v.x; t[r][jg * 4 + 1] = v.y;
        t[r][jg * 4 + 2] = v.z; t[r][jg * 4 + 3] = v.w;
    }
    __syncthreads();
    {
        const int jr = tid >> 3, kg = tid & 7;  // j-row, k-group
        short4 o;
        o.x = (short)f2bf(t[kg * 4 + 0][jr]);
        o.y = (short)f2bf(t[kg * 4 + 1][jr]);
        o.z = (short)f2bf(t[kg * 4 + 2][jr]);
        o.w = (short)f2bf(t[kg * 4 + 3][jr]);
        *(short4*)&wt[(size_t)(l * HD + jt * 32 + jr) * K2 + kt * 32 + kg * 4] = o;
    }
}

// ---- prep: Wslt[j][k] = bf16(Wsl[k][j])
__global__ void prep_wsl(const float* __restrict__ Wsl, unsigned short* __restrict__ wslt) {
    const int tid = threadIdx.x;
    const int j = tid >> 4, k0 = (tid & 15) * 16;
#pragma unroll
    for (int t = 0; t < 16; ++t)
        wslt[j * HD + k0 + t] = f2bf(Wsl[(k0 + t) * NI + j]);
}

struct __align__(16) SMem {
    unsigned short h[BB * NI * ASH];  // 33792 B, bf16 h per element (in-place updated)
    unsigned short gm[BB * HD];       // 2048 B, bf16 column means
    float sl[BB][NI][NI + 1];         // 4352 B
    float x0[BB * NI];                // 256 B
    float gmean[BB];
};
static_assert(sizeof(SMem) <= 65536, "LDS must fit 64KB per-workgroup launch limit");

__global__ __launch_bounds__(256, 2)
void eqslater_mfma(const float* __restrict__ x0g,
                   const float* __restrict__ Win,
                   const float* __restrict__ bin,
                   const float* __restrict__ bmid,
                   const float* __restrict__ bsl,
                   const float* __restrict__ width,
                   const unsigned short* __restrict__ wt,    // [3][256][512] bf16
                   const unsigned short* __restrict__ wslt,  // [16][256] bf16
                   float* __restrict__ out) {
    __shared__ SMem sm;
    const int tid = threadIdx.x;
    const int bbase = blockIdx.x * BB;

    if (tid < BB * NI) sm.x0[tid] = x0g[bbase * NI + tid];
    __syncthreads();
    if (tid < BB) {
        float s = 0.f;
#pragma unroll
        for (int n = 0; n < NI; ++n) s += sm.x0[tid * NI + n];
        sm.gmean[tid] = s * 0.0625f;
    }
    __syncthreads();

    // ---- input layer (fp32 VALU): h = tanh(x0*W0 + g*W1 + b), stored bf16
    {
        const int j = tid;
        const float w0 = Win[j], w1 = Win[HD + j], bj = bin[j];
#pragma unroll 4
        for (int r = 0; r < BB * NI; ++r) {
            float pre = fmaf(sm.x0[r], w0, fmaf(sm.gmean[r >> 4], w1, bj));
            sm.h[r * ASH + j] = f2bf(fast_tanh(pre));
        }
    }
    __syncthreads();
    // From here each wave owns one element: no barriers until LU staging.

    const int e = tid >> 6;   // wave = element
    const int l = tid & 63;
    const int c = l & 15;     // A-row / B-col / C-col
    const int g = l >> 4;     // k-group (8 contiguous k per frag)

    bf16x8 af[8], ag[8];

    for (int layer = 0; layer < NMID; ++layer) {
        // ---- gm: column means of own h (fp32 accumulate, bf16 store)
        {
            const int c0 = l * 4;
            float s0 = 0, s1 = 0, s2 = 0, s3 = 0;
#pragma unroll
            for (int r = 0; r < NI; ++r) {
                short4 v = *(const short4*)&sm.h[(e * NI + r) * ASH + c0];
                s0 += bf2f((unsigned short)v.x);
                s1 += bf2f((unsigned short)v.y);
                s2 += bf2f((unsigned short)v.z);
                s3 += bf2f((unsigned short)v.w);
            }
            short4 o;
            o.x = (short)f2bf(s0 * 0.0625f); o.y = (short)f2bf(s1 * 0.0625f);
            o.z = (short)f2bf(s2 * 0.0625f); o.w = (short)f2bf(s3 * 0.0625f);
            *(short4*)&sm.gm[e * HD + c0] = o;
        }
        // ---- A fragments in registers (h rows k<256; gm broadcast k>=256)
#pragma unroll
        for (int s = 0; s < 8; ++s)
            af[s] = *(const bf16x8*)&sm.h[(e * NI + c) * ASH + 32 * s + 8 * g];
#pragma unroll
        for (int s = 0; s < 8; ++s)
            ag[s] = *(const bf16x8*)&sm.gm[e * HD + 32 * s + 8 * g];

        const unsigned short* wl = wt + (size_t)layer * HD * K2;
        const float* bml = bmid + layer * HD;

        bf16x8 bq[16];
        {
            const unsigned short* bp = wl + (size_t)c * K2 + 8 * g;
#pragma unroll
            for (int s = 0; s < 16; ++s) bq[s] = *(const bf16x8*)(bp + 32 * s);
        }
        float biasc = bml[c];

#pragma unroll 1
        for (int n = 0; n < 16; ++n) {
            f32x4 acc0 = {0.f, 0.f, 0.f, 0.f}, acc1 = {0.f, 0.f, 0.f, 0.f};
#pragma unroll
            for (int s = 0; s < 8; ++s)
                acc0 = __builtin_amdgcn_mfma_f32_16x16x32_bf16(af[s], bq[s], acc0, 0, 0, 0);
#pragma unroll
            for (int s = 0; s < 8; ++s)
                acc1 = __builtin_amdgcn_mfma_f32_16x16x32_bf16(ag[s], bq[8 + s], acc1, 0, 0, 0);
            float biasn = 0.f;
            if (n < 15) {   // issue next n-tile's B loads; epilogue hides latency
                const unsigned short* bp = wl + (size_t)(16 * (n + 1) + c) * K2 + 8 * g;
#pragma unroll
                for (int s = 0; s < 16; ++s) bq[s] = *(const bf16x8*)(bp + 32 * s);
                biasn = bml[16 * (n + 1) + c];
            }
            // ---- epilogue: C[row=4g+q][col=c], j = 16n+c (verified m89 C-layout)
            const int j = 16 * n + c;
#pragma unroll
            for (int q = 0; q < 4; ++q) {
                const int row = 4 * g + q;
                unsigned short res = sm.h[(e * NI + row) * ASH + j];
                float o = fast_tanh(acc0[q] + acc1[q] + biasc) + bf2f(res);
                sm.h[(e * NI + row) * ASH + j] = f2bf(o);
            }
            biasc = biasn;
        }
    }

    // ---- slater head: 16x16 = h(16x256) @ Wsl(256x16) + bsl, via 8 MFMA
    {
#pragma unroll
        for (int s = 0; s < 8; ++s)
            af[s] = *(const bf16x8*)&sm.h[(e * NI + c) * ASH + 32 * s + 8 * g];
        f32x4 a0 = {0.f, 0.f, 0.f, 0.f}, a1 = {0.f, 0.f, 0.f, 0.f};
#pragma unroll
        for (int s = 0; s < 4; ++s) {
            bf16x8 b0 = *(const bf16x8*)&wslt[c * HD + 32 * (2 * s) + 8 * g];
            bf16x8 b1 = *(const bf16x8*)&wslt[c * HD + 32 * (2 * s + 1) + 8 * g];
            a0 = __builtin_amdgcn_mfma_f32_16x16x32_bf16(af[2 * s], b0, a0, 0, 0, 0);
            a1 = __builtin_amdgcn_mfma_f32_16x16x32_bf16(af[2 * s + 1], b1, a1, 0, 0, 0);
        }
        const float bs = bsl[c];
#pragma unroll
        for (int q = 0; q < 4; ++q)
            sm.sl[e][4 * g + q][c] = a0[q] + a1[q] + bs;
    }
    __syncthreads();   // cheap; guarantees sl visibility before LU

    // ---- per-wave slogdet: register LU w/ partial pivoting (R4-verified)
    const int w = e;
    const int i = c;   // row, 4x duplicated across lanes
    {
        float M[16];
#pragma unroll
        for (int j = 0; j < 16; ++j) M[j] = sm.sl[w][i][j];

        float dsign = 1.f, logabs = 0.f;
#pragma unroll
        for (int k = 0; k < 16; ++k) {
            float myv = (i >= k) ? __builtin_fabsf(M[k]) : -1.f;
            float maxv = myv;
#pragma unroll
            for (int off = 32; off > 0; off >>= 1)
                maxv = fmaxf(maxv, __shfl_xor(maxv, off));
            unsigned long long bal = __ballot(myv == maxv);
            int p = (__ffsll((long long)bal) - 1) & 15;

            if (p != k) {
                dsign = -dsign;
#pragma unroll
                for (int j = 0; j < 16; ++j) {
                    float vk = __shfl(M[j], k);
                    float vp = __shfl(M[j], p);
                    if (i == k) M[j] = vp;
                    if (i == p) M[j] = vk;
                }
            }
            float piv = __shfl(M[k], k);
            // NaN guard (singular matrix): finite logabs, no 0/0 poison.
            float ap = fmaxf(__builtin_fabsf(piv), 1e-35f);
            logabs += __logf(ap);
            if (piv < 0.f) dsign = -dsign;
            float spiv = __builtin_copysignf(ap, piv);
            float mi = __fdividef(M[k], spiv);
#pragma unroll
            for (int j = k + 1; j < 16; ++j) {
                float vkj = __shfl(M[j], k);
                if (i > k) M[j] = __builtin_fmaf(-mi, vkj, M[j]);
            }
        }

        float xv = (l < NI) ? sm.x0[w * NI + l] : 0.f;
        float sq = xv * xv;
#pragma unroll
        for (int off = 8; off > 0; off >>= 1) sq += __shfl_xor(sq, off);

        if (l == 0) {
            out[bbase + w] = dsign;
            out[BTOT + bbase + w] = logabs - HALF_LOGFACT - width[0] * sq;
        }
    }
}

extern "C" void kernel_launch(void* const* d_in, const int* in_sizes, int n_in,
                              void* d_out, int out_size, void* d_ws, size_t ws_size,
                              hipStream_t stream) {
    const float* x0   = (const float*)d_in[0];
    const float* Win  = (const float*)d_in[1];
    const float* bin  = (const float*)d_in[2];
    const float* Wmid = (const float*)d_in[3];
    const float* bmid = (const float*)d_in[4];
    const float* Wsl  = (const float*)d_in[5];
    const float* bsl  = (const float*)d_in[6];
    const float* wid  = (const float*)d_in[7];
    float* out = (float*)d_out;

    unsigned short* wtb   = (unsigned short*)d_ws;           // 786432 B
    unsigned short* wsltb = wtb + 3 * HD * K2;               // + 8192 B

    hipLaunchKernelGGL(prep_wt,  dim3(384), dim3(256), 0, stream, Wmid, wtb);
    hipLaunchKernelGGL(prep_wsl, dim3(1),   dim3(256), 0, stream, Wsl, wsltb);
    hipLaunchKernelGGL(eqslater_mfma, dim3(BTOT / BB), dim3(256), 0, stream,
                       x0, Win, bin, bmid, bsl, wid, wtb, wsltb, out);
}

// Round 6
// 449.084 us; speedup vs baseline: 5.0332x; 3.0782x over previous
//
#include <hip/hip_runtime.h>

// Problem constants
#define BTOT 16384
#define NI   16
#define HD   256
#define BB   4            // elements per block = waves per block
#define NMID 3
#define ASH  264          // h LDS row stride in bf16 (528B, 16B-aligned, bank-spread)
#define SLS  20           // slater scratch row stride (floats; 16B-aligned rows)
#define NCHUNK 49         // 48 mid chunks + 1 slater chunk
#define HALF_LOGFACT 15.3359295387f  // 0.5 * ln(16!)

typedef short  bf16x8 __attribute__((ext_vector_type(8)));
typedef float  f32x4  __attribute__((ext_vector_type(4)));

__device__ __forceinline__ unsigned short f2bf(float f) {
    unsigned u = __builtin_bit_cast(unsigned, f);
    u += 0x7FFFu + ((u >> 16) & 1u);          // RNE
    return (unsigned short)(u >> 16);
}
__device__ __forceinline__ float bf2f(unsigned short h) {
    return __builtin_bit_cast(float, (unsigned)h << 16);
}
__device__ __forceinline__ float fast_tanh(float x) {
    float ax = __builtin_fabsf(x);
    float e  = __expf(-2.0f * ax);
    float t  = __fdividef(1.0f - e, 1.0f + e);
    return __builtin_copysignf(t, x);
}

// ---- prep: chunked fragment-order weights.
// Chunk fc<48: (layer=fc>>4, ch=fc&15): dst[kg*128 + j*8 + kk] = Wmid[layer][8kg+kk][ch*16+j],
//   kg in [0,64) (K=512). Chunk 48: Wsl, kg in [0,32) (K=256), rest zero.
__global__ void prep_w(const float* __restrict__ Wmid, const float* __restrict__ Wsl,
                       unsigned short* __restrict__ wtc) {
    const int b = blockIdx.x;       // 0..48
    const int t = threadIdx.x;
    unsigned short* dst = wtc + (size_t)b * 8192;
    if (b < 48) {
        const int layer = b >> 4, ch = b & 15;
        const float* src = Wmid + (size_t)layer * (2 * HD * HD);
#pragma unroll 4
        for (int v = 0; v < 32; ++v) {
            int o = t * 32 + v;
            int kk = o & 7, j = (o >> 3) & 15, kg = o >> 7;
            dst[o] = f2bf(src[(8 * kg + kk) * HD + ch * 16 + j]);
        }
    } else {
#pragma unroll 4
        for (int v = 0; v < 32; ++v) {
            int o = t * 32 + v;
            int kk = o & 7, j = (o >> 3) & 15, kg = o >> 7;
            dst[o] = (kg < 32) ? f2bf(Wsl[(8 * kg + kk) * NI + j]) : (unsigned short)0;
        }
    }
}

struct __align__(16) SMem {
    unsigned short wtile[8192];           // 16384 B: staged W chunk [kg][16 j][8 k]
    union {
        unsigned short h[BB * NI * ASH];  // 33792 B: bf16 h (in-place across layers)
        float slf[BB][NI * ASH / 2];      // per-element slater scratch (reuses own h)
    } u;
    unsigned short gm[BB * HD];           // 2048 B
    float x0[BB * NI];                    // 256 B
    float gmean[BB];                      // 16 B
};
static_assert(sizeof(SMem) <= 53248, "need <= 52KB-ish for 3 blocks/CU");

__global__ __launch_bounds__(256, 3)
void eqslater_mfma(const float* __restrict__ x0g,
                   const float* __restrict__ Win,
                   const float* __restrict__ bin,
                   const float* __restrict__ bmid,
                   const float* __restrict__ bsl,
                   const float* __restrict__ width,
                   const unsigned short* __restrict__ wtc,
                   float* __restrict__ out) {
    __shared__ SMem sm;
    const int tid = threadIdx.x;
    const int bbase = blockIdx.x * BB;
    const int e = tid >> 6;   // wave = element
    const int l = tid & 63;
    const int c = l & 15;     // A-row / B-col / C-col
    const int g = l >> 4;     // k-group

    // ---- prefetch chunk 0 into regs (hides under input layer)
    const uint4* wsrc = (const uint4*)wtc;
    uint4 pr0 = wsrc[tid], pr1 = wsrc[tid + 256], pr2 = wsrc[tid + 512], pr3 = wsrc[tid + 768];

    if (tid < BB * NI) sm.x0[tid] = x0g[bbase * NI + tid];
    __syncthreads();
    if (tid < BB) {
        float s = 0.f;
#pragma unroll
        for (int n = 0; n < NI; ++n) s += sm.x0[tid * NI + n];
        sm.gmean[tid] = s * 0.0625f;
    }
    __syncthreads();

    // ---- input layer (fp32 VALU): h = tanh(x0*W0 + g*W1 + b), stored bf16
    {
        const int j = tid;
        const float w0 = Win[j], w1 = Win[HD + j], bj = bin[j];
#pragma unroll 4
        for (int r = 0; r < BB * NI; ++r) {
            float pre = fmaf(sm.x0[r], w0, fmaf(sm.gmean[r >> 4], w1, bj));
            sm.u.h[r * ASH + j] = f2bf(fast_tanh(pre));
        }
    }
    __syncthreads();   // h written cross-wave; waves go private after this

    bf16x8 af[8], ag[8];
    int fc = 0;

#pragma unroll 1
    for (int layer = 0; layer < NMID; ++layer) {
        // ---- gm: column means of own h (wave-private; in-wave DS ordering)
        {
            const int c0 = l * 4;
            float s0 = 0, s1 = 0, s2 = 0, s3 = 0;
#pragma unroll
            for (int r = 0; r < NI; ++r) {
                short4 v = *(const short4*)&sm.u.h[(e * NI + r) * ASH + c0];
                s0 += bf2f((unsigned short)v.x);
                s1 += bf2f((unsigned short)v.y);
                s2 += bf2f((unsigned short)v.z);
                s3 += bf2f((unsigned short)v.w);
            }
            short4 o;
            o.x = (short)f2bf(s0 * 0.0625f); o.y = (short)f2bf(s1 * 0.0625f);
            o.z = (short)f2bf(s2 * 0.0625f); o.w = (short)f2bf(s3 * 0.0625f);
            *(short4*)&sm.gm[e * HD + c0] = o;
        }
        // ---- A fragments (h rows for k<256; gm broadcast for k>=256)
#pragma unroll
        for (int s = 0; s < 8; ++s) {
            af[s] = *(const bf16x8*)&sm.u.h[(e * NI + c) * ASH + 32 * s + 8 * g];
            ag[s] = *(const bf16x8*)&sm.gm[e * HD + 32 * s + 8 * g];
        }

        const float* bml = bmid + layer * HD;

#pragma unroll 1
        for (int ch = 0; ch < 16; ++ch) {
            __syncthreads();   // all waves done reading wtile (prev chunk)
            {
                uint4* wt4 = (uint4*)sm.wtile;
                wt4[tid] = pr0; wt4[tid + 256] = pr1;
                wt4[tid + 512] = pr2; wt4[tid + 768] = pr3;
            }
            ++fc;
            if (fc < NCHUNK) {   // issue next chunk's global loads (hide under compute)
                const uint4* p = wsrc + (size_t)fc * 1024 + tid;
                pr0 = p[0]; pr1 = p[256]; pr2 = p[512]; pr3 = p[768];
            }
            float biasv = bml[ch * 16 + c];
            __syncthreads();   // wtile ready

            f32x4 p0 = {0.f,0.f,0.f,0.f}, p1 = {0.f,0.f,0.f,0.f};
            f32x4 p2 = {0.f,0.f,0.f,0.f}, p3 = {0.f,0.f,0.f,0.f};
#pragma unroll
            for (int s = 0; s < 4; ++s) {   // 4 independent MFMA chains of 4
                bf16x8 b0 = *(const bf16x8*)&sm.wtile[(4 * (2 * s)     + g) * 128 + c * 8];
                bf16x8 b1 = *(const bf16x8*)&sm.wtile[(4 * (2 * s + 1) + g) * 128 + c * 8];
                bf16x8 b2 = *(const bf16x8*)&sm.wtile[(32 + 4 * (2 * s)     + g) * 128 + c * 8];
                bf16x8 b3 = *(const bf16x8*)&sm.wtile[(32 + 4 * (2 * s + 1) + g) * 128 + c * 8];
                p0 = __builtin_amdgcn_mfma_f32_16x16x32_bf16(af[2 * s],     b0, p0, 0, 0, 0);
                p1 = __builtin_amdgcn_mfma_f32_16x16x32_bf16(af[2 * s + 1], b1, p1, 0, 0, 0);
                p2 = __builtin_amdgcn_mfma_f32_16x16x32_bf16(ag[2 * s],     b2, p2, 0, 0, 0);
                p3 = __builtin_amdgcn_mfma_f32_16x16x32_bf16(ag[2 * s + 1], b3, p3, 0, 0, 0);
            }
            f32x4 av = (p0 + p1) + (p2 + p3);

            // ---- epilogue: C[row=4g+q][col=c], global col j = 16ch+c
            const int j = ch * 16 + c;
#pragma unroll
            for (int q = 0; q < 4; ++q) {
                const int hidx = (e * NI + 4 * g + q) * ASH + j;
                float o = fast_tanh(av[q] + biasv) + bf2f(sm.u.h[hidx]);
                sm.u.h[hidx] = f2bf(o);
            }
        }
    }

    // ---- slater head: frags from final h (before wtile overwrite barrier)
#pragma unroll
    for (int s = 0; s < 8; ++s)
        af[s] = *(const bf16x8*)&sm.u.h[(e * NI + c) * ASH + 32 * s + 8 * g];
    __syncthreads();
    {
        uint4* wt4 = (uint4*)sm.wtile;
        wt4[tid] = pr0; wt4[tid + 256] = pr1;
        wt4[tid + 512] = pr2; wt4[tid + 768] = pr3;
    }
    __syncthreads();
    {
        f32x4 q0 = {0.f,0.f,0.f,0.f}, q1 = {0.f,0.f,0.f,0.f};
#pragma unroll
        for (int s = 0; s < 4; ++s) {
            bf16x8 b0 = *(const bf16x8*)&sm.wtile[(4 * (2 * s)     + g) * 128 + c * 8];
            bf16x8 b1 = *(const bf16x8*)&sm.wtile[(4 * (2 * s + 1) + g) * 128 + c * 8];
            q0 = __builtin_amdgcn_mfma_f32_16x16x32_bf16(af[2 * s],     b0, q0, 0, 0, 0);
            q1 = __builtin_amdgcn_mfma_f32_16x16x32_bf16(af[2 * s + 1], b1, q1, 0, 0, 0);
        }
        f32x4 sv = q0 + q1;
        const float bs = bsl[c];
        float* slp = &sm.u.slf[e][0];   // own-element region: own h is dead, own wave only
#pragma unroll
        for (int q = 0; q < 4; ++q)
            slp[(4 * g + q) * SLS + c] = sv[q] + bs;
    }

    // ---- per-wave slogdet: register LU w/ partial pivoting (R4-verified)
    {
        const float* slp = &sm.u.slf[e][0];
        const int i = c;   // row, 4x duplicated across lanes
        float M[16];
#pragma unroll
        for (int jj = 0; jj < 4; ++jj) {
            float4 v = *(const float4*)&slp[i * SLS + 4 * jj];
            M[4 * jj] = v.x; M[4 * jj + 1] = v.y; M[4 * jj + 2] = v.z; M[4 * jj + 3] = v.w;
        }

        float dsign = 1.f, logabs = 0.f;
#pragma unroll
        for (int k = 0; k < 16; ++k) {
            float myv = (i >= k) ? __builtin_fabsf(M[k]) : -1.f;
            float maxv = myv;
#pragma unroll
            for (int off = 32; off > 0; off >>= 1)
                maxv = fmaxf(maxv, __shfl_xor(maxv, off));
            unsigned long long bal = __ballot(myv == maxv);
            int p = (__ffsll((long long)bal) - 1) & 15;

            if (p != k) {
                dsign = -dsign;
#pragma unroll
                for (int j = 0; j < 16; ++j) {
                    float vk = __shfl(M[j], k);
                    float vp = __shfl(M[j], p);
                    if (i == k) M[j] = vp;
                    if (i == p) M[j] = vk;
                }
            }
            float piv = __shfl(M[k], k);
            // NaN guard (singular matrix): finite logabs, no 0/0 poison.
            float ap = fmaxf(__builtin_fabsf(piv), 1e-35f);
            logabs += __logf(ap);
            if (piv < 0.f) dsign = -dsign;
            float spiv = __builtin_copysignf(ap, piv);
            float mi = __fdividef(M[k], spiv);
#pragma unroll
            for (int j = k + 1; j < 16; ++j) {
                float vkj = __shfl(M[j], k);
                if (i > k) M[j] = __builtin_fmaf(-mi, vkj, M[j]);
            }
        }

        float xv = (l < NI) ? sm.x0[e * NI + l] : 0.f;
        float sq = xv * xv;
#pragma unroll
        for (int off = 8; off > 0; off >>= 1) sq += __shfl_xor(sq, off);

        if (l == 0) {
            out[bbase + e] = dsign;
            out[BTOT + bbase + e] = logabs - HALF_LOGFACT - width[0] * sq;
        }
    }
}

extern "C" void kernel_launch(void* const* d_in, const int* in_sizes, int n_in,
                              void* d_out, int out_size, void* d_ws, size_t ws_size,
                              hipStream_t stream) {
    const float* x0   = (const float*)d_in[0];
    const float* Win  = (const float*)d_in[1];
    const float* bin  = (const float*)d_in[2];
    const float* Wmid = (const float*)d_in[3];
    const float* bmid = (const float*)d_in[4];
    const float* Wsl  = (const float*)d_in[5];
    const float* bsl  = (const float*)d_in[6];
    const float* wid  = (const float*)d_in[7];
    float* out = (float*)d_out;

    unsigned short* wtc = (unsigned short*)d_ws;   // 49 * 16384 B = 802816 B

    hipLaunchKernelGGL(prep_w, dim3(NCHUNK), dim3(256), 0, stream, Wmid, Wsl, wtc);
    hipLaunchKernelGGL(eqslater_mfma, dim3(BTOT / BB), dim3(256), 0, stream,
                       x0, Win, bin, bmid, bsl, wid, wtc, out);
}